// Round 6
// baseline (268.288 us; speedup 1.0000x reference)
//
#include <hip/hip_runtime.h>

// Butterfly network: 12 stages over rows of 4096 fp32.
// y[p] <- W[s][p][0]*y[p] + W[s][p][1]*y[p^d],  d = 1<<s, s = 0..11
//
// Radix-8 decomposition: p = [P3|P2|P1|P0] (3 bits each).
// Block = 512 threads, RPB = 4 rows, 8 positions/thread -> v[4][8] = 32 VGPRs.
//
//   L1: p = 8t + i             (thread [P3P2P1], i=P0) -> stages 0..2
//   L2: p = t6*512+t3*64+8i+t0 (thread [P3P2P0], i=P1) -> stages 3..5
//   L3: p = t6*512+64i+8t3+t0  (thread [P3P1P0], i=P2) -> stages 6..8
//   L4: p = 512i + t           (thread [P2P1P0], i=P3) -> stages 9..11 + store
//
// Depth-1 software pipeline on the weight loads: two 8xfloat2 register
// buffers; stage s+1's 8 loads are issued before stage s's butterflies,
// fully peeled across all 12 stages. Round-4 counters showed the per-stage
// {load -> waitcnt -> compute} serialization exposes ~250cy of L2 latency
// x12 stages per wave (VALUBusy 23%, occ 42%, dur 105us = 2.5x HBM floor).
// T1/T2 are lgkm-only fences so prefetches survive them; T3's barrier drain
// overlaps the in-flight S9 load.
//
// LDS padded to 48 KB ON PURPOSE: caps the CU at 3 blocks (24 waves), so the
// backend's occupancy-chasing register allocator budgets ~85 VGPRs instead of
// squeezing to 64 (the round-2/3 spill mechanism: 32 KB LDS -> 4-block target
// -> 64-reg cap -> scratch). Natural pressure here is ~75-84.
// Spill tripwire: WRITE_SIZE must be exactly 131072 KB (output only).
//
// Transitions via LDS (float2 = row-PAIR packed, 2 passes each):
//   T1 (P0<->P1), T2 (P1<->P2): intra-wave (P3 fixed, per-wave-disjoint slots)
//     -> no __syncthreads, only s_waitcnt lgkmcnt(0) + sched_barrier(0)
//     (DS ops are in-order per wave; sched_barrier stops hipcc hoisting
//     anything past the fence — guide rule #18).
//   T3 (P2<->P3): cross-wave -> 3 x __syncthreads.
// Swizzle slot(P3,P2,P1,P0): bank bits b0..2 = P0^P1^P2, b3 = P1[0]^P2[1];
// bijective, 4 lanes/bank-pair (the wave64 b64 floor) on all six patterns.

constexpr int LROW = 4096;
constexpr int RPB  = 4;
constexpr int NBLK = 8192 / RPB;   // 2048 blocks x 512 threads

__device__ __forceinline__ int slotf(int P3, int P2, int P1, int P0) {
    const int b012 = (P0 ^ P1 ^ P2) & 7;
    const int b3   = (P1 ^ (P2 >> 1)) & 1;
    const int U    = (P3 << 5) | (P2 << 2) | (P1 >> 1);
    return (U << 4) | (b3 << 3) | b012;
}

// phase-A weight load (positions contiguous): 4 x dwordx4
template<int S>
__device__ __forceinline__ void loadA(float2 (&w)[8], const float* __restrict__ W, int t) {
    const float4* q4 = reinterpret_cast<const float4*>(W + (size_t)S * 8192 + 16 * t);
    #pragma unroll
    for (int m = 0; m < 4; ++m) {
        const float4 q = q4[m];
        w[2*m]   = make_float2(q.x, q.y);
        w[2*m+1] = make_float2(q.z, q.w);
    }
}

// generic strided weight load: 8 x dwordx2, STEP in positions (== float2s)
template<int S, int STEP>
__device__ __forceinline__ void loadG(float2 (&w)[8], const float* __restrict__ W, int pbase) {
    const float2* q2 = reinterpret_cast<const float2*>(W) + (size_t)S * 4096 + pbase;
    #pragma unroll
    for (int m = 0; m < 8; ++m) w[m] = q2[m * STEP];
}

template<int DL>
__device__ __forceinline__ void stage(float (&v)[RPB][8], const float2 (&w)[8]) {
    #pragma unroll
    for (int g = 0; g < 8; g += 2*DL)
        #pragma unroll
        for (int m = 0; m < DL; ++m) {
            const int a = g + m, c = a + DL;
            #pragma unroll
            for (int r = 0; r < RPB; ++r) {
                const float va = v[r][a], vb = v[r][c];
                v[r][a] = w[a].x * va + w[a].y * vb;
                v[r][c] = w[c].x * vb + w[c].y * va;
            }
        }
}

__global__ __launch_bounds__(512)
void butterfly12_kernel(const float* __restrict__ x,
                        const float* __restrict__ W,
                        float* __restrict__ out)
{
    __shared__ float2 lds[6144];   // 48 KB (4096 used; pad caps CU at 3 blocks)

    const int t  = threadIdx.x;    // 9 bits
    const int t6 = t >> 6;         // wave id
    const int t3 = (t >> 3) & 7;
    const int t0 = t & 7;
    const size_t row0 = (size_t)blockIdx.x * RPB;

    float v[RPB][8];
    float2 wbA[8], wbB[8];

    // ---- load x: L1, p = 8t + i, 2 x float4 per row ----
    #pragma unroll
    for (int r = 0; r < RPB; ++r) {
        const float4* xr = reinterpret_cast<const float4*>(x + (row0 + r) * LROW + 8 * t);
        const float4 qa = xr[0], qb = xr[1];
        v[r][0]=qa.x; v[r][1]=qa.y; v[r][2]=qa.z; v[r][3]=qa.w;
        v[r][4]=qb.x; v[r][5]=qb.y; v[r][6]=qb.z; v[r][7]=qb.w;
    }

    const int pB = t6*512 + t3*64 + t0;   // L2 base position (i=0)
    const int pC = t6*512 + t3*8  + t0;   // L3 base position (i=0)

    // ---- phase A: stages 0..2 (digit P0), pipelined ----
    loadA<0>(wbA, W, t);
    loadA<1>(wbB, W, t);
    stage<1>(v, wbA);          // S0
    loadA<2>(wbA, W, t);
    stage<2>(v, wbB);          // S1
    loadG<3, 8>(wbB, W, pB);   // S3 prefetch (phase B) -- survives T1 (lgkm-only)
    stage<4>(v, wbA);          // S2

    // ---- T1: L1 -> L2 (intra-wave) ----
    #pragma unroll
    for (int h = 0; h < 2; ++h) {
        asm volatile("" ::: "memory");
        #pragma unroll
        for (int i = 0; i < 8; ++i)
            lds[slotf(t6, t3, t0, i)] = make_float2(v[2*h][i], v[2*h+1][i]);
        asm volatile("s_waitcnt lgkmcnt(0)" ::: "memory");
        __builtin_amdgcn_sched_barrier(0);
        #pragma unroll
        for (int j = 0; j < 8; ++j) {
            const float2 q = lds[slotf(t6, t3, j, t0)];
            v[2*h][j] = q.x; v[2*h+1][j] = q.y;
        }
    }

    // ---- phase B: stages 3..5 (digit P1), pipelined ----
    loadG<4, 8>(wbA, W, pB);
    stage<1>(v, wbB);          // S3
    loadG<5, 8>(wbB, W, pB);
    stage<2>(v, wbA);          // S4
    loadG<6, 64>(wbA, W, pC);  // S6 prefetch (phase C) -- survives T2
    stage<4>(v, wbB);          // S5

    // ---- T2: L2 -> L3 (intra-wave; writes reuse this thread's T1-read slots) ----
    #pragma unroll
    for (int h = 0; h < 2; ++h) {
        asm volatile("" ::: "memory");
        #pragma unroll
        for (int j = 0; j < 8; ++j)
            lds[slotf(t6, t3, j, t0)] = make_float2(v[2*h][j], v[2*h+1][j]);
        asm volatile("s_waitcnt lgkmcnt(0)" ::: "memory");
        __builtin_amdgcn_sched_barrier(0);
        #pragma unroll
        for (int k = 0; k < 8; ++k) {
            const float2 q = lds[slotf(t6, k, t3, t0)];
            v[2*h][k] = q.x; v[2*h+1][k] = q.y;
        }
    }

    // ---- phase C: stages 6..8 (digit P2), pipelined ----
    loadG<7, 64>(wbB, W, pC);
    stage<1>(v, wbA);          // S6
    loadG<8, 64>(wbA, W, pC);
    stage<2>(v, wbB);          // S7
    loadG<9, 512>(wbB, W, t);  // S9 prefetch (phase D) -- completes under T3 barrier
    stage<4>(v, wbA);          // S8

    // ---- T3: L3 -> L4 (cross-wave: P2 <-> P3) ----
    {
        #pragma unroll
        for (int k = 0; k < 8; ++k)     // writes reuse this thread's T2-read slots
            lds[slotf(t6, k, t3, t0)] = make_float2(v[0][k], v[1][k]);
        __syncthreads();
        #pragma unroll
        for (int m = 0; m < 8; ++m) {
            const float2 q = lds[slotf(m, t6, t3, t0)];
            v[0][m] = q.x; v[1][m] = q.y;
        }
        __syncthreads();                // all pass-1 reads done before overwrite
        #pragma unroll
        for (int k = 0; k < 8; ++k)
            lds[slotf(t6, k, t3, t0)] = make_float2(v[2][k], v[3][k]);
        __syncthreads();
        #pragma unroll
        for (int m = 0; m < 8; ++m) {
            const float2 q = lds[slotf(m, t6, t3, t0)];
            v[2][m] = q.x; v[3][m] = q.y;
        }
    }

    // ---- phase D: stages 9..11 (digit P3), pipelined ----
    loadG<10, 512>(wbA, W, t);
    stage<1>(v, wbB);          // S9
    loadG<11, 512>(wbB, W, t);
    stage<2>(v, wbA);          // S10
    stage<4>(v, wbB);          // S11

    // ---- store: L4, p = 512m + t => fully coalesced dword stores ----
    #pragma unroll
    for (int r = 0; r < RPB; ++r) {
        float* orow = out + (row0 + r) * LROW;
        #pragma unroll
        for (int m = 0; m < 8; ++m)
            orow[m*512 + t] = v[r][m];
    }
}

extern "C" void kernel_launch(void* const* d_in, const int* in_sizes, int n_in,
                              void* d_out, int out_size, void* d_ws, size_t ws_size,
                              hipStream_t stream) {
    const float* x = (const float*)d_in[0];   // (8192, 4096) fp32
    const float* W = (const float*)d_in[1];   // (12, 4096, 2) fp32
    float* out = (float*)d_out;               // (8192, 4096) fp32

    butterfly12_kernel<<<NBLK, 512, 0, stream>>>(x, W, out);
}